// Round 11
// baseline (532.451 us; speedup 1.0000x reference)
//
#include <hip/hip_runtime.h>
#include <hip/hip_bf16.h>

#define B_N 16
#define LQ_N 2048
#define LK_N 2048
#define D_N 64

typedef __attribute__((ext_vector_type(8))) __bf16 bf16x8;
typedef __attribute__((ext_vector_type(4))) float f32x4;
typedef __attribute__((ext_vector_type(2))) unsigned u32x2;
typedef __attribute__((ext_vector_type(4))) unsigned u32x4;

__device__ __forceinline__ unsigned cvt_pk_bf16(float lo, float hi) {
  unsigned r;
  asm("v_cvt_pk_bf16_f32 %0, %1, %2" : "=v"(r) : "v"(lo), "v"(hi));
  return r;
}

__device__ __forceinline__ void gl_lds16(const float* g, float* l) {
  __builtin_amdgcn_global_load_lds(
      (const __attribute__((address_space(1))) void*)g,
      (__attribute__((address_space(3))) void*)l, 16, 0, 0);
}

#define WAIT_VMC(N)  do { asm volatile("s_waitcnt vmcnt(" #N ")" ::: "memory"); __builtin_amdgcn_sched_barrier(0); } while (0)
#define WAIT_LGKM0() do { asm volatile("s_waitcnt lgkmcnt(0)" ::: "memory");    __builtin_amdgcn_sched_barrier(0); } while (0)
#define SBAR()       __builtin_amdgcn_sched_barrier(0)

// ws layout (floats): [0..2047] red1 sums, [2048..4095] red1 maxes,
// [4096..4099] scalars, [8192..8192+32767] rowsums (SUM -> EMIT). ~160 KB.

// ---------- pass 1: global sum & max of time_diff ----------
__global__ __launch_bounds__(256) void red1_kernel(const float* __restrict__ td,
                                                   float* __restrict__ ws) {
  const int tid = threadIdx.x;
  const int gid = blockIdx.x * 256 + tid;
  float s = 0.f, mx = -1e30f;
  const float4* p = reinterpret_cast<const float4*>(td);
  for (int i = gid; i < 16777216; i += 524288) {
    float4 x = p[i];
    s += (x.x + x.y) + (x.z + x.w);
    mx = fmaxf(mx, fmaxf(fmaxf(x.x, x.y), fmaxf(x.z, x.w)));
  }
#pragma unroll
  for (int m = 1; m < 64; m <<= 1) {
    s += __shfl_xor(s, m, 64);
    mx = fmaxf(mx, __shfl_xor(mx, m, 64));
  }
  __shared__ float ss[4], sm[4];
  if ((tid & 63) == 0) { ss[tid >> 6] = s; sm[tid >> 6] = mx; }
  __syncthreads();
  if (tid == 0) {
    ws[blockIdx.x]        = (ss[0] + ss[1]) + (ss[2] + ss[3]);
    ws[2048 + blockIdx.x] = fmaxf(fmaxf(sm[0], sm[1]), fmaxf(sm[2], sm[3]));
  }
}

// final reduce + scalar prep + mask-layout detection (byte vs int32 bool)
__global__ __launch_bounds__(256) void red2_kernel(const float* __restrict__ tpw,
                                                   const unsigned* __restrict__ mku,
                                                   float* __restrict__ ws) {
  const int tid = threadIdx.x;
  double s = 0.0; float mx = -1e30f;
  for (int i = tid; i < 2048; i += 256) { s += (double)ws[i]; mx = fmaxf(mx, ws[2048 + i]); }
#pragma unroll
  for (int m = 1; m < 64; m <<= 1) {
    s += __shfl_xor(s, m, 64);
    mx = fmaxf(mx, __shfl_xor(mx, m, 64));
  }
  unsigned big = 0;
  for (int i = tid; i < 1024; i += 256) big |= (mku[i] > 1u) ? 1u : 0u;
  const int anyw = __any(big != 0);
  __shared__ double sd[4]; __shared__ float sm[4]; __shared__ int sa[4];
  if ((tid & 63) == 0) { sd[tid >> 6] = s; sm[tid >> 6] = mx; sa[tid >> 6] = anyw; }
  __syncthreads();
  if (tid == 0) {
    double tot = (sd[0] + sd[1]) + (sd[2] + sd[3]);
    float m4 = fmaxf(fmaxf(sm[0], sm[1]), fmaxf(sm[2], sm[3]));
    double mean = tot / 67108864.0;
    float inv_mean = (float)(1.0 / mean);
    float sp = log1pf(__expf(tpw[0]));
    ws[4096] = inv_mean;
    ws[4098] = (sa[0] | sa[1] | sa[2] | sa[3]) ? 1.f : 0.f;  // 1 = byte mask, 0 = int32
    ws[4099] = 2.718281828459045f + sp * m4 * inv_mean;      // ec = e + bias_c
  }
}

// ---------- SUM: QK^T(swapped) + bias + mask + exp2 -> rowsums ----------
// 512 thr (8 waves), 16 q-rows/block, chunk=128 j (16 j/wave), 16 chunks.
// NO cross-phase state (E eliminated): lean regs -> high occupancy. K via
// global_load_lds SINGLE-buffer (K is L3-resident; 1-iter margin covers L3 lat).
__global__ __launch_bounds__(512)
void sum_kernel(
    const float* __restrict__ q, const float* __restrict__ kp,
    const float* __restrict__ td, const unsigned char* __restrict__ maskb,
    const float* __restrict__ tmwp, float* __restrict__ ws) {

  __shared__ float Kb[8][1024];              // 32 KB: per-wave K chunk (single buffer)
  __shared__ float rsum[8][16];

  const int tid  = threadIdx.x;
  const int w    = tid >> 6;
  const int lane = tid & 63;
  const int lrow = lane & 15;
  const int lgrp = lane >> 4;

  const int b     = blockIdx.x >> 7;
  const int qbase = (blockIdx.x & 127) << 4;

  const float inv_mean = ws[4096];
  const float ec       = ws[4099];
  const float tmw      = tmwp[0];
  const float sc       = tmw * 2.0813689810056077f;      // tmw * log2e / ln2
  const int   msh      = (ws[4098] != 0.f) ? 0 : 2;

  const unsigned qrow = (unsigned)(b * LQ_N + qbase + lrow);
  const unsigned tdo0 = (qrow << 11) + (unsigned)(w * 16 + lgrp * 4);
  const unsigned kvo0 = ((unsigned)b << 17) + ((unsigned)w << 10);
  const unsigned pA = (lgrp << 6) + ((lrow ^ lgrp)       << 2);
  const unsigned pB = (lgrp << 6) + ((lrow ^ (lgrp + 4)) << 2);

  auto kdma = [&](int c) {
    const unsigned base = kvo0 + (unsigned)c * 8192u;
    gl_lds16(kp + (base         + pA), &Kb[w][0]);
    gl_lds16(kp + (base +  256u + pB), &Kb[w][256]);
    gl_lds16(kp + (base +  512u + pA), &Kb[w][512]);
    gl_lds16(kp + (base +  768u + pB), &Kb[w][768]);
  };
  auto ldtd = [&](int c, f32x4* tdv, unsigned* mk4) {
    const unsigned to = tdo0 + (unsigned)c * 128u;
    *tdv = __builtin_nontemporal_load(reinterpret_cast<const f32x4*>(td + to));
    if (msh == 0) {
      *mk4 = *reinterpret_cast<const unsigned*>(maskb + to);
    } else {
      u32x4 m = __builtin_nontemporal_load(
          reinterpret_cast<const u32x4*>(maskb + ((size_t)to << 2)));
      *mk4 = (m[0] & 1u) | ((m[1] & 1u) << 8) | ((m[2] & 1u) << 16) | ((m[3] & 1u) << 24);
    }
  };

  // Q fragments: direct global load (L3-resident), one-time, into regs
  const float* qb = q + ((size_t)qrow << 6);
  f32x4 q0a = *reinterpret_cast<const f32x4*>(qb + lgrp * 8);
  f32x4 q0b = *reinterpret_cast<const f32x4*>(qb + lgrp * 8 + 4);
  f32x4 q1a = *reinterpret_cast<const f32x4*>(qb + 32 + lgrp * 8);
  f32x4 q1b = *reinterpret_cast<const f32x4*>(qb + 32 + lgrp * 8 + 4);
  SBAR();
  // prologue: Kd(0)[4], L(0)[2], L(1)[2]
  kdma(0); SBAR();
  f32x4    tdb[2];
  unsigned mkb[2];
  ldtd(0, &tdb[0], &mkb[0]); SBAR();
  ldtd(1, &tdb[1], &mkb[1]); SBAR();

  // Q retired when newer(Kd0,L0,L1)=8 outstanding
  WAIT_VMC(8);
  const float qscale = 0.18033688011112042f;             // 0.125 * log2e
  bf16x8 qa[2];
  {
    u32x4 k0 = { cvt_pk_bf16(q0a[0]*qscale, q0a[1]*qscale), cvt_pk_bf16(q0a[2]*qscale, q0a[3]*qscale),
                 cvt_pk_bf16(q0b[0]*qscale, q0b[1]*qscale), cvt_pk_bf16(q0b[2]*qscale, q0b[3]*qscale) };
    u32x4 k1 = { cvt_pk_bf16(q1a[0]*qscale, q1a[1]*qscale), cvt_pk_bf16(q1a[2]*qscale, q1a[3]*qscale),
                 cvt_pk_bf16(q1b[0]*qscale, q1b[1]*qscale), cvt_pk_bf16(q1b[2]*qscale, q1b[3]*qscale) };
    qa[0] = __builtin_bit_cast(bf16x8, k0);
    qa[1] = __builtin_bit_cast(bf16x8, k1);
  }

  float rs = 0.f;
#pragma unroll
  for (int c = 0; c < 16; ++c) {
    // W_K: newer than Kd(c): c=0 -> {L0,L1}=4; steady -> {L(c+1)}=2; c=15 -> 0
    if (c == 0)       { WAIT_VMC(4); }
    else if (c == 15) { WAIT_VMC(0); }
    else              { WAIT_VMC(2); }

    f32x4 acc = {0.f, 0.f, 0.f, 0.f};
#pragma unroll
    for (int h = 0; h < 2; ++h) {
      const int g0 = (h * 8 + lgrp * 2 + 0) ^ (lrow & 7);
      const int g1 = (h * 8 + lgrp * 2 + 1) ^ (lrow & 7);
      f32x4 ka = *(const f32x4*)&Kb[w][lrow * 64 + g0 * 4];
      f32x4 kc = *(const f32x4*)&Kb[w][lrow * 64 + g1 * 4];
      u32x4 kd = { cvt_pk_bf16(ka[0], ka[1]), cvt_pk_bf16(ka[2], ka[3]),
                   cvt_pk_bf16(kc[0], kc[1]), cvt_pk_bf16(kc[2], kc[3]) };
      acc = __builtin_amdgcn_mfma_f32_16x16x32_bf16(__builtin_bit_cast(bf16x8, kd), qa[h],
                                                    acc, 0, 0, 0);
    }
    WAIT_LGKM0();                              // Kb[w] reusable
    if (c < 15) { kdma(c + 1); SBAR(); }
    if (c == 0) { WAIT_VMC(6); }               // L0 retired (newer: L1,Kd1)

    const f32x4    tv  = tdb[c & 1];
    const unsigned mk4 = mkb[c & 1];
#pragma unroll
    for (int i = 0; i < 4; ++i) {
      const float z  = __builtin_fmaf(tv[i], inv_mean, ec);
      const float l2 = __builtin_amdgcn_logf(z);
      const float r  = __builtin_amdgcn_rcpf(l2);
      const float sv = __builtin_fmaf(sc, r, acc[i]);
      const float e  = ((mk4 >> (8 * i)) & 0xffu) ? 0.f : __builtin_amdgcn_exp2f(sv);
      rs += e;
    }
    if (c < 14) { ldtd(c + 2, &tdb[c & 1], &mkb[c & 1]); SBAR(); }
  }

  // rowsum: reduce over lgrp, then cross-wave, write to ws
  rs += __shfl_xor(rs, 16, 64);
  rs += __shfl_xor(rs, 32, 64);
  if (lgrp == 0) rsum[w][lrow] = rs;
  __syncthreads();
  if (tid < 16) {
    float s = 0.f;
#pragma unroll
    for (int w2 = 0; w2 < 8; ++w2) s += rsum[w2][tid];
    ws[8192 + (unsigned)(b * LQ_N + qbase) + tid] = s;
  }
}

// ---------- EMIT: recompute exp, normalize, write attn + PV ----------
// Same layout as SUM; adds V (gl_lds single-buffer) + attn NT store + O accumulate.
// No E state; invl read from ws rowsums.
__global__ __launch_bounds__(512)
void emit_kernel(
    const float* __restrict__ q, const float* __restrict__ kp, const float* __restrict__ vp,
    const float* __restrict__ td, const unsigned char* __restrict__ maskb,
    const float* __restrict__ tmwp, const float* __restrict__ ws,
    float* __restrict__ out, float* __restrict__ attn) {

  __shared__ float Kb[8][1024];              // 32 KB K chunk (single buffer / O-reduce)
  __shared__ float Vb[8][1024];              // 32 KB V chunk (single buffer)
  __shared__ unsigned short Ps[8][16 * 24];  // per-wave P bridge

  const int tid  = threadIdx.x;
  const int w    = tid >> 6;
  const int lane = tid & 63;
  const int lrow = lane & 15;
  const int lgrp = lane >> 4;

  const int b     = blockIdx.x >> 7;
  const int qbase = (blockIdx.x & 127) << 4;

  const float inv_mean = ws[4096];
  const float ec       = ws[4099];
  const float tmw      = tmwp[0];
  const float sc       = tmw * 2.0813689810056077f;
  const int   msh      = (ws[4098] != 0.f) ? 0 : 2;

  const unsigned qrow = (unsigned)(b * LQ_N + qbase + lrow);
  const unsigned tdo0 = (qrow << 11) + (unsigned)(w * 16 + lgrp * 4);
  const unsigned kvo0 = ((unsigned)b << 17) + ((unsigned)w << 10);
  const unsigned pA = (lgrp << 6) + ((lrow ^ lgrp)       << 2);
  const unsigned pB = (lgrp << 6) + ((lrow ^ (lgrp + 4)) << 2);

  auto kdma = [&](int c) {
    const unsigned base = kvo0 + (unsigned)c * 8192u;
    gl_lds16(kp + (base         + pA), &Kb[w][0]);
    gl_lds16(kp + (base +  256u + pB), &Kb[w][256]);
    gl_lds16(kp + (base +  512u + pA), &Kb[w][512]);
    gl_lds16(kp + (base +  768u + pB), &Kb[w][768]);
  };
  auto vdma = [&](int c) {
    const unsigned base = kvo0 + (unsigned)c * 8192u;
    gl_lds16(vp + (base         + pA), &Vb[w][0]);
    gl_lds16(vp + (base +  256u + pB), &Vb[w][256]);
    gl_lds16(vp + (base +  512u + pA), &Vb[w][512]);
    gl_lds16(vp + (base +  768u + pB), &Vb[w][768]);
  };
  auto ldtd = [&](int c, f32x4* tdv, unsigned* mk4) {
    const unsigned to = tdo0 + (unsigned)c * 128u;
    *tdv = __builtin_nontemporal_load(reinterpret_cast<const f32x4*>(td + to));
    if (msh == 0) {
      *mk4 = *reinterpret_cast<const unsigned*>(maskb + to);
    } else {
      u32x4 m = __builtin_nontemporal_load(
          reinterpret_cast<const u32x4*>(maskb + ((size_t)to << 2)));
      *mk4 = (m[0] & 1u) | ((m[1] & 1u) << 8) | ((m[2] & 1u) << 16) | ((m[3] & 1u) << 24);
    }
  };

  // Q direct + invl
  const float* qb = q + ((size_t)qrow << 6);
  f32x4 q0a = *reinterpret_cast<const f32x4*>(qb + lgrp * 8);
  f32x4 q0b = *reinterpret_cast<const f32x4*>(qb + lgrp * 8 + 4);
  f32x4 q1a = *reinterpret_cast<const f32x4*>(qb + 32 + lgrp * 8);
  f32x4 q1b = *reinterpret_cast<const f32x4*>(qb + 32 + lgrp * 8 + 4);
  const float rsv = ws[8192 + qrow];
  SBAR();
  // prologue: Kd0[4], Vd0[4], L0[2], L1[2]
  kdma(0); SBAR();
  vdma(0); SBAR();
  f32x4    tdb[2];
  unsigned mkb[2];
  ldtd(0, &tdb[0], &mkb[0]); SBAR();
  ldtd(1, &tdb[1], &mkb[1]); SBAR();

  WAIT_VMC(12);                                // Q + rsv retired (12 newer ops)
  const float invl = __fdividef(1.f, rsv);
  const float qscale = 0.18033688011112042f;
  bf16x8 qa[2];
  {
    u32x4 k0 = { cvt_pk_bf16(q0a[0]*qscale, q0a[1]*qscale), cvt_pk_bf16(q0a[2]*qscale, q0a[3]*qscale),
                 cvt_pk_bf16(q0b[0]*qscale, q0b[1]*qscale), cvt_pk_bf16(q0b[2]*qscale, q0b[3]*qscale) };
    u32x4 k1 = { cvt_pk_bf16(q1a[0]*qscale, q1a[1]*qscale), cvt_pk_bf16(q1a[2]*qscale, q1a[3]*qscale),
                 cvt_pk_bf16(q1b[0]*qscale, q1b[1]*qscale), cvt_pk_bf16(q1b[2]*qscale, q1b[3]*qscale) };
    qa[0] = __builtin_bit_cast(bf16x8, k0);
    qa[1] = __builtin_bit_cast(bf16x8, k1);
  }

  f32x4 oacc[4];
#pragma unroll
  for (int n = 0; n < 4; ++n) oacc[n] = {0.f, 0.f, 0.f, 0.f};
  const u32x4 zz = {0u, 0u, 0u, 0u};

#pragma unroll
  for (int c = 0; c < 16; ++c) {
    // W_K: newer than Kd(c): c=0 -> {Vd0,L0,L1}=8; steady -> {Vd(c),L(c+1),S(c-1)}=7;
    // c=15 -> {Vd15,S14}=5
    if (c == 0)       { WAIT_VMC(8); }
    else if (c == 15) { WAIT_VMC(5); }
    else              { WAIT_VMC(7); }

    f32x4 acc = {0.f, 0.f, 0.f, 0.f};
#pragma unroll
    for (int h = 0; h < 2; ++h) {
      const int g0 = (h * 8 + lgrp * 2 + 0) ^ (lrow & 7);
      const int g1 = (h * 8 + lgrp * 2 + 1) ^ (lrow & 7);
      f32x4 ka = *(const f32x4*)&Kb[w][lrow * 64 + g0 * 4];
      f32x4 kc = *(const f32x4*)&Kb[w][lrow * 64 + g1 * 4];
      u32x4 kd = { cvt_pk_bf16(ka[0], ka[1]), cvt_pk_bf16(ka[2], ka[3]),
                   cvt_pk_bf16(kc[0], kc[1]), cvt_pk_bf16(kc[2], kc[3]) };
      acc = __builtin_amdgcn_mfma_f32_16x16x32_bf16(__builtin_bit_cast(bf16x8, kd), qa[h],
                                                    acc, 0, 0, 0);
    }
    WAIT_LGKM0();                              // Kb[w] reusable
    if (c < 15) { kdma(c + 1); SBAR(); }
    if (c == 0) { WAIT_VMC(6); }               // L0 retired (also implies Vd0 retired)

    const f32x4    tv  = tdb[c & 1];
    const unsigned mk4 = mkb[c & 1];
    f32x4 pv;
#pragma unroll
    for (int i = 0; i < 4; ++i) {
      const float z  = __builtin_fmaf(tv[i], inv_mean, ec);
      const float l2 = __builtin_amdgcn_logf(z);
      const float r  = __builtin_amdgcn_rcpf(l2);
      const float sv = __builtin_fmaf(sc, r, acc[i]);
      const float e  = ((mk4 >> (8 * i)) & 0xffu) ? 0.f : __builtin_amdgcn_exp2f(sv);
      pv[i] = e * invl;
    }

    // P bridge (same-wave DS ordering)
    const unsigned d01 = cvt_pk_bf16(pv[0], pv[1]);
    const unsigned d23 = cvt_pk_bf16(pv[2], pv[3]);
    *reinterpret_cast<u32x2*>(&Ps[w][lrow * 24 + lgrp * 4]) = u32x2{ d01, d23 };
    bf16x8 pa;
    if (lgrp < 2) pa = *(const bf16x8*)&Ps[w][lrow * 24 + lgrp * 8];
    else          pa = __builtin_bit_cast(bf16x8, zz);

    // W_V: newer than Vd(c): steady (after Kd(c+1)) -> {L(c+1),S(c-1),Kd(c+1)}=7;
    // c=0 covered by VMC(6) above; c=15 -> {S14}=1
    if (c == 15)     { WAIT_VMC(1); }
    else if (c >= 1) { WAIT_VMC(7); }

#pragma unroll
    for (int n = 0; n < 4; ++n) {
      u32x4 vd;
      if (lgrp < 2) {
        float vv[8];
#pragma unroll
        for (int e = 0; e < 8; ++e) {
          const int r    = lgrp * 8 + e;
          const int dcol = n * 16 + lrow;
          const int slot = (dcol >> 2) ^ (r & 7);
          vv[e] = Vb[w][r * 64 + slot * 4 + (dcol & 3)];
        }
        vd = u32x4{ cvt_pk_bf16(vv[0], vv[1]), cvt_pk_bf16(vv[2], vv[3]),
                    cvt_pk_bf16(vv[4], vv[5]), cvt_pk_bf16(vv[6], vv[7]) };
      } else {
        vd = zz;
      }
      oacc[n] = __builtin_amdgcn_mfma_f32_16x16x32_bf16(pa, __builtin_bit_cast(bf16x8, vd),
                                                        oacc[n], 0, 0, 0);
    }
    WAIT_LGKM0();                              // Vb[w] reads done
    if (c < 15) { vdma(c + 1); SBAR(); }
    if (c < 14) { ldtd(c + 2, &tdb[c & 1], &mkb[c & 1]); SBAR(); }

    __builtin_nontemporal_store(pv, reinterpret_cast<f32x4*>(attn + tdo0 + (unsigned)c * 128u));
  }

  // cross-wave O reduction (reuse Kb)
  __syncthreads();
#pragma unroll
  for (int n = 0; n < 4; ++n)
#pragma unroll
    for (int i = 0; i < 4; ++i)
      Kb[w][(lgrp * 4 + i) * 64 + n * 16 + lrow] = oacc[n][i];
  __syncthreads();
  for (int i2 = tid; i2 < 1024; i2 += 512) {
    float s = 0.f;
#pragma unroll
    for (int w2 = 0; w2 < 8; ++w2) s += Kb[w2][i2];
    out[((size_t)(b * LQ_N + qbase) << 6) + i2] = s;
  }
}

extern "C" void kernel_launch(void* const* d_in, const int* in_sizes, int n_in,
                              void* d_out, int out_size, void* d_ws, size_t ws_size,
                              hipStream_t stream) {
  const float* q   = (const float*)d_in[0];
  const float* k   = (const float*)d_in[1];
  const float* v   = (const float*)d_in[2];
  const float* td  = (const float*)d_in[3];
  const unsigned char* mask = (const unsigned char*)d_in[4];
  const float* tpw = (const float*)d_in[5];
  const float* tmw = (const float*)d_in[6];
  float* out  = (float*)d_out;
  float* attn = out + (size_t)B_N * LQ_N * D_N;
  float* wsf  = (float*)d_ws;

  red1_kernel<<<2048, 256, 0, stream>>>(td, wsf);
  red2_kernel<<<1, 256, 0, stream>>>(tpw, (const unsigned*)mask, wsf);
  sum_kernel<<<2048, 512, 0, stream>>>(q, k, td, mask, tmw, wsf);
  emit_kernel<<<2048, 512, 0, stream>>>(q, k, v, td, mask, tmw, wsf, out, attn);
}

// Round 12
// 406.519 us; speedup vs baseline: 1.3098x; 1.3098x over previous
//
#include <hip/hip_runtime.h>
#include <hip/hip_bf16.h>

#define B_N 16
#define LQ_N 2048
#define LK_N 2048
#define D_N 64

typedef __attribute__((ext_vector_type(8))) __bf16 bf16x8;
typedef __attribute__((ext_vector_type(4))) float f32x4;
typedef __attribute__((ext_vector_type(2))) unsigned u32x2;
typedef __attribute__((ext_vector_type(4))) unsigned u32x4;

__device__ __forceinline__ unsigned cvt_pk_bf16(float lo, float hi) {
  unsigned r;
  asm("v_cvt_pk_bf16_f32 %0, %1, %2" : "=v"(r) : "v"(lo), "v"(hi));
  return r;
}

// ---------- pass 1: global sum & max of time_diff ----------
__global__ __launch_bounds__(256) void red1_kernel(const float* __restrict__ td,
                                                   float* __restrict__ ws) {
  const int tid = threadIdx.x;
  const int gid = blockIdx.x * 256 + tid;
  float s = 0.f, mx = -1e30f;
  const float4* p = reinterpret_cast<const float4*>(td);
  for (int i = gid; i < 16777216; i += 524288) {
    float4 x = p[i];
    s += (x.x + x.y) + (x.z + x.w);
    mx = fmaxf(mx, fmaxf(fmaxf(x.x, x.y), fmaxf(x.z, x.w)));
  }
#pragma unroll
  for (int m = 1; m < 64; m <<= 1) {
    s += __shfl_xor(s, m, 64);
    mx = fmaxf(mx, __shfl_xor(mx, m, 64));
  }
  __shared__ float ss[4], sm[4];
  if ((tid & 63) == 0) { ss[tid >> 6] = s; sm[tid >> 6] = mx; }
  __syncthreads();
  if (tid == 0) {
    ws[blockIdx.x]        = (ss[0] + ss[1]) + (ss[2] + ss[3]);
    ws[2048 + blockIdx.x] = fmaxf(fmaxf(sm[0], sm[1]), fmaxf(sm[2], sm[3]));
  }
}

// final reduce + scalar prep + mask-layout detection (byte vs int32 bool)
__global__ __launch_bounds__(256) void red2_kernel(const float* __restrict__ tpw,
                                                   const unsigned* __restrict__ mku,
                                                   float* __restrict__ ws) {
  const int tid = threadIdx.x;
  double s = 0.0; float mx = -1e30f;
  for (int i = tid; i < 2048; i += 256) { s += (double)ws[i]; mx = fmaxf(mx, ws[2048 + i]); }
#pragma unroll
  for (int m = 1; m < 64; m <<= 1) {
    s += __shfl_xor(s, m, 64);
    mx = fmaxf(mx, __shfl_xor(mx, m, 64));
  }
  unsigned big = 0;
  for (int i = tid; i < 1024; i += 256) big |= (mku[i] > 1u) ? 1u : 0u;
  const int anyw = __any(big != 0);
  __shared__ double sd[4]; __shared__ float sm[4]; __shared__ int sa[4];
  if ((tid & 63) == 0) { sd[tid >> 6] = s; sm[tid >> 6] = mx; sa[tid >> 6] = anyw; }
  __syncthreads();
  if (tid == 0) {
    double tot = (sd[0] + sd[1]) + (sd[2] + sd[3]);
    float m4 = fmaxf(fmaxf(sm[0], sm[1]), fmaxf(sm[2], sm[3]));
    double mean = tot / 67108864.0;
    float inv_mean = (float)(1.0 / mean);
    float sp = log1pf(__expf(tpw[0]));
    ws[4096] = inv_mean;
    ws[4098] = (sa[0] | sa[1] | sa[2] | sa[3]) ? 1.f : 0.f;  // 1 = byte mask, 0 = int32
    ws[4099] = 2.718281828459045f + sp * m4 * inv_mean;      // ec = e + bias_c
  }
}

// ---------- fused attn: QK^T + bias + mask + softmax + attn-write + PV ----------
// 1024 thr (16 waves), 16 q-rows/block, 8 chunks of 256 j (16 j per wave).
// Design (r12): NO manual vmcnt/sched_barrier, NO global_load_lds — compiler-scheduled.
//  - E (un-normalized exp) lives in LDS (64 KB, wave-private, 2-way-free) -> no E regs,
//    no spill, single td/mask pass (the r4-r10 spill/occupancy dilemma removed at root)
//  - K & Q fragments: direct global->register loads (L3-resident, auto-prefetched)
//  - V: reg-staged into LDS with write-side XOR swizzle (plain ds ops)
//  - swapped QK^T (mfma(K,Q)): lane holds q-row=lrow, 4 consecutive j -> td/mask/attn
//    are float4/u32/f32x4 vector ops
__global__ __launch_bounds__(1024)
void attn_kernel(
    const float* __restrict__ q, const float* __restrict__ kp, const float* __restrict__ vp,
    const float* __restrict__ td, const unsigned char* __restrict__ maskb,
    const float* __restrict__ tmwp, const float* __restrict__ ws,
    float* __restrict__ out, float* __restrict__ attn) {

  __shared__ u32x2 Elds[8192];               // 64 KB: [c][tid] -> (c<<10)+tid
  __shared__ float Vb[16][1024];             // 64 KB: per-wave V chunk (single buffer)
  __shared__ unsigned short Ps[16][16 * 24]; // 12 KB: per-wave P bridge
  __shared__ float rsum[16][16];             // 1 KB

  const int tid  = threadIdx.x;
  const int w    = tid >> 6;
  const int lane = tid & 63;
  const int lrow = lane & 15;
  const int lgrp = lane >> 4;

  const int b     = blockIdx.x >> 7;
  const int qbase = (blockIdx.x & 127) << 4;

  const float inv_mean = ws[4096];
  const float ec       = ws[4099];
  const float tmw      = tmwp[0];
  const float sc       = tmw * 2.0813689810056077f;      // tmw * log2e / ln2
  const int   msh      = (ws[4098] != 0.f) ? 0 : 2;

  const unsigned qrow  = (unsigned)(b * LQ_N + qbase + lrow);
  const unsigned tdo0  = (qrow << 11) + (unsigned)(w * 16 + lgrp * 4);
  const unsigned kvo0  = ((unsigned)b << 17);

  // ---- Q fragments: direct loads + cvt (8 regs) ----
  const float qscale = 0.18033688011112042f;             // 0.125 * log2e
  bf16x8 qa[2];
  {
    const float* qb = q + ((size_t)qrow << 6) + lgrp * 8;
    f32x4 a0 = *reinterpret_cast<const f32x4*>(qb);
    f32x4 a1 = *reinterpret_cast<const f32x4*>(qb + 4);
    f32x4 a2 = *reinterpret_cast<const f32x4*>(qb + 32);
    f32x4 a3 = *reinterpret_cast<const f32x4*>(qb + 36);
    u32x4 k0 = { cvt_pk_bf16(a0[0]*qscale, a0[1]*qscale), cvt_pk_bf16(a0[2]*qscale, a0[3]*qscale),
                 cvt_pk_bf16(a1[0]*qscale, a1[1]*qscale), cvt_pk_bf16(a1[2]*qscale, a1[3]*qscale) };
    u32x4 k1 = { cvt_pk_bf16(a2[0]*qscale, a2[1]*qscale), cvt_pk_bf16(a2[2]*qscale, a2[3]*qscale),
                 cvt_pk_bf16(a3[0]*qscale, a3[1]*qscale), cvt_pk_bf16(a3[2]*qscale, a3[3]*qscale) };
    qa[0] = __builtin_bit_cast(bf16x8, k0);
    qa[1] = __builtin_bit_cast(bf16x8, k1);
  }

  // K fragment loader: lane reads its 16 f32 (4x f32x4) for A[row=lrow][k]
  auto ldk = [&](int c, f32x4* kf) {
    const float* kr = kp + kvo0 + (unsigned)((c * 256 + w * 16 + lrow) << 6) + lgrp * 8;
    kf[0] = *reinterpret_cast<const f32x4*>(kr);         // h=0, k lo
    kf[1] = *reinterpret_cast<const f32x4*>(kr + 4);     // h=0, k hi
    kf[2] = *reinterpret_cast<const f32x4*>(kr + 32);    // h=1, k lo
    kf[3] = *reinterpret_cast<const f32x4*>(kr + 36);    // h=1, k hi
  };
  // td (NT float4) + mask (cached, 4-wide)
  auto ldtd = [&](int c, f32x4* tdv, unsigned* mk4) {
    const unsigned to = tdo0 + (unsigned)c * 256u;
    *tdv = __builtin_nontemporal_load(reinterpret_cast<const f32x4*>(td + to));
    if (msh == 0) {
      *mk4 = *reinterpret_cast<const unsigned*>(maskb + to);
    } else {
      u32x4 m = *reinterpret_cast<const u32x4*>(maskb + ((size_t)to << 2));
      *mk4 = (m[0] & 1u) | ((m[1] & 1u) << 8) | ((m[2] & 1u) << 16) | ((m[3] & 1u) << 24);
    }
  };

  // ---- phase 1: QK^T(swapped) + bias + mask + exp2 -> E in LDS ----
  float rs = 0.f;
  {
    f32x4    kf[2][4];
    f32x4    tdb[2];
    unsigned mkb[2];
    ldk(0, kf[0]);
    ldtd(0, &tdb[0], &mkb[0]);
#pragma unroll
    for (int c = 0; c < 8; ++c) {
      if (c < 7) { ldk(c + 1, kf[(c + 1) & 1]); ldtd(c + 1, &tdb[(c + 1) & 1], &mkb[(c + 1) & 1]); }

      const f32x4* kc = kf[c & 1];
      u32x4 kd0 = { cvt_pk_bf16(kc[0][0], kc[0][1]), cvt_pk_bf16(kc[0][2], kc[0][3]),
                    cvt_pk_bf16(kc[1][0], kc[1][1]), cvt_pk_bf16(kc[1][2], kc[1][3]) };
      u32x4 kd1 = { cvt_pk_bf16(kc[2][0], kc[2][1]), cvt_pk_bf16(kc[2][2], kc[2][3]),
                    cvt_pk_bf16(kc[3][0], kc[3][1]), cvt_pk_bf16(kc[3][2], kc[3][3]) };
      f32x4 acc = {0.f, 0.f, 0.f, 0.f};
      acc = __builtin_amdgcn_mfma_f32_16x16x32_bf16(__builtin_bit_cast(bf16x8, kd0), qa[0], acc, 0, 0, 0);
      acc = __builtin_amdgcn_mfma_f32_16x16x32_bf16(__builtin_bit_cast(bf16x8, kd1), qa[1], acc, 0, 0, 0);

      const f32x4    tv  = tdb[c & 1];
      const unsigned mk4 = mkb[c & 1];
      float e4[4];
#pragma unroll
      for (int i = 0; i < 4; ++i) {
        const float z  = __builtin_fmaf(tv[i], inv_mean, ec);
        const float l2 = __builtin_amdgcn_logf(z);
        const float r  = __builtin_amdgcn_rcpf(l2);
        const float sv = __builtin_fmaf(sc, r, acc[i]);
        const float e  = ((mk4 >> (8 * i)) & 0xffu) ? 0.f : __builtin_amdgcn_exp2f(sv);
        e4[i] = e;
        rs += e;
      }
      Elds[(c << 10) + tid] = u32x2{ cvt_pk_bf16(e4[0], e4[1]), cvt_pk_bf16(e4[2], e4[3]) };
    }
  }

  // ---- row sums -> invl ----
  rs += __shfl_xor(rs, 16, 64);
  rs += __shfl_xor(rs, 32, 64);
  if (lgrp == 0) rsum[w][lrow] = rs;
  __syncthreads();
  float invl;
  {
    float s = 0.f;
#pragma unroll
    for (int w2 = 0; w2 < 16; ++w2) s += rsum[w2][lrow];
    invl = __fdividef(1.f, s);
  }

  // ---- phase 2: normalize E -> attn write + PV ----
  // V loader: 16 rows x 64 f32 per wave chunk, coalesced to regs
  auto ldv = [&](int c, f32x4* vr) {
#pragma unroll
    for (int t = 0; t < 4; ++t) {
      const int r = t * 4 + lgrp;
      vr[t] = *reinterpret_cast<const f32x4*>(
          vp + kvo0 + (unsigned)((c * 256 + w * 16 + r) << 6) + lrow * 4);
    }
  };
  // V store: write-side XOR swizzle matching the gather
  auto stv = [&](const f32x4* vr) {
#pragma unroll
    for (int t = 0; t < 4; ++t) {
      const int r    = t * 4 + lgrp;
      const int slot = lrow ^ (r & 7);
      *reinterpret_cast<f32x4*>(&Vb[w][r * 64 + slot * 4]) = vr[t];
    }
  };

  f32x4 oacc[4];
#pragma unroll
  for (int n = 0; n < 4; ++n) oacc[n] = {0.f, 0.f, 0.f, 0.f};
  const u32x4 zz = {0u, 0u, 0u, 0u};

  {
    f32x4 vr[4];
    ldv(0, vr);
    stv(vr);
#pragma unroll
    for (int c = 0; c < 8; ++c) {
      // normalized P from Elds
      const u32x2 ee = Elds[(c << 10) + tid];
      f32x4 pv;
      pv[0] = __uint_as_float(ee[0] << 16)         * invl;
      pv[1] = __uint_as_float(ee[0] & 0xffff0000u) * invl;
      pv[2] = __uint_as_float(ee[1] << 16)         * invl;
      pv[3] = __uint_as_float(ee[1] & 0xffff0000u) * invl;

      // attn write (NT, streaming)
      __builtin_nontemporal_store(pv, reinterpret_cast<f32x4*>(attn + tdo0 + (unsigned)c * 256u));

      // P bridge (wave-private; same-wave DS ordering)
      const unsigned d01 = cvt_pk_bf16(pv[0], pv[1]);
      const unsigned d23 = cvt_pk_bf16(pv[2], pv[3]);
      *reinterpret_cast<u32x2*>(&Ps[w][lrow * 24 + lgrp * 4]) = u32x2{ d01, d23 };
      bf16x8 pa;
      if (lgrp < 2) pa = *(const bf16x8*)&Ps[w][lrow * 24 + lgrp * 8];
      else          pa = __builtin_bit_cast(bf16x8, zz);

      // prefetch next V chunk into regs (global loads issue early)
      f32x4 vrN[4];
      if (c < 7) ldv(c + 1, vrN);

      // PV: gather V from Vb (k = lgrp*8+e < 16 real; upper half zero)
#pragma unroll
      for (int n = 0; n < 4; ++n) {
        u32x4 vd;
        if (lgrp < 2) {
          float vv[8];
#pragma unroll
          for (int e = 0; e < 8; ++e) {
            const int r    = lgrp * 8 + e;
            const int dcol = n * 16 + lrow;
            const int slot = (dcol >> 2) ^ (r & 7);
            vv[e] = Vb[w][r * 64 + slot * 4 + (dcol & 3)];
          }
          vd = u32x4{ cvt_pk_bf16(vv[0], vv[1]), cvt_pk_bf16(vv[2], vv[3]),
                      cvt_pk_bf16(vv[4], vv[5]), cvt_pk_bf16(vv[6], vv[7]) };
        } else {
          vd = zz;
        }
        oacc[n] = __builtin_amdgcn_mfma_f32_16x16x32_bf16(pa, __builtin_bit_cast(bf16x8, vd),
                                                          oacc[n], 0, 0, 0);
      }

      // stage next V chunk (compiler orders the ds_writes after this chunk's gathers)
      if (c < 7) stv(vrN);
    }
  }

  // ---- cross-wave O reduction (reuse Vb) ----
  __syncthreads();
#pragma unroll
  for (int n = 0; n < 4; ++n)
#pragma unroll
    for (int i = 0; i < 4; ++i)
      Vb[w][(lgrp * 4 + i) * 64 + n * 16 + lrow] = oacc[n][i];
  __syncthreads();
  {
    float s = 0.f;
#pragma unroll
    for (int w2 = 0; w2 < 16; ++w2) s += Vb[w2][tid];
    out[((size_t)(b * LQ_N + qbase) << 6) + tid] = s;
  }
}

extern "C" void kernel_launch(void* const* d_in, const int* in_sizes, int n_in,
                              void* d_out, int out_size, void* d_ws, size_t ws_size,
                              hipStream_t stream) {
  const float* q   = (const float*)d_in[0];
  const float* k   = (const float*)d_in[1];
  const float* v   = (const float*)d_in[2];
  const float* td  = (const float*)d_in[3];
  const unsigned char* mask = (const unsigned char*)d_in[4];
  const float* tpw = (const float*)d_in[5];
  const float* tmw = (const float*)d_in[6];
  float* out  = (float*)d_out;
  float* attn = out + (size_t)B_N * LQ_N * D_N;
  float* wsf  = (float*)d_ws;

  red1_kernel<<<2048, 256, 0, stream>>>(td, wsf);
  red2_kernel<<<1, 256, 0, stream>>>(tpw, (const unsigned*)mask, wsf);
  attn_kernel<<<2048, 1024, 0, stream>>>(q, k, v, td, mask, tmw, wsf, out, attn);
}

// Round 14
// 328.595 us; speedup vs baseline: 1.6204x; 1.2371x over previous
//
#include <hip/hip_runtime.h>
#include <hip/hip_bf16.h>

#define B_N 16
#define LQ_N 2048
#define LK_N 2048
#define D_N 64

typedef __attribute__((ext_vector_type(8))) __bf16 bf16x8;
typedef __attribute__((ext_vector_type(4))) float f32x4;
typedef __attribute__((ext_vector_type(2))) unsigned u32x2;
typedef __attribute__((ext_vector_type(4))) unsigned u32x4;

__device__ __forceinline__ unsigned cvt_pk_bf16(float lo, float hi) {
  unsigned r;
  asm("v_cvt_pk_bf16_f32 %0, %1, %2" : "=v"(r) : "v"(lo), "v"(hi));
  return r;
}

__device__ __forceinline__ void gl_lds16(const float* g, float* l) {
  __builtin_amdgcn_global_load_lds(
      (const __attribute__((address_space(1))) void*)g,
      (__attribute__((address_space(3))) void*)l, 16, 0, 0);
}

#define WAIT_VMC(N)  do { asm volatile("s_waitcnt vmcnt(" #N ")" ::: "memory"); __builtin_amdgcn_sched_barrier(0); } while (0)
#define WAIT_LGKM0() do { asm volatile("s_waitcnt lgkmcnt(0)" ::: "memory");    __builtin_amdgcn_sched_barrier(0); } while (0)
#define SBAR()       __builtin_amdgcn_sched_barrier(0)

// ---------- pass 1: global sum & max of time_diff ----------
__global__ __launch_bounds__(256) void red1_kernel(const float* __restrict__ td,
                                                   float* __restrict__ ws) {
  const int tid = threadIdx.x;
  const int gid = blockIdx.x * 256 + tid;
  float s = 0.f, mx = -1e30f;
  const float4* p = reinterpret_cast<const float4*>(td);
  for (int i = gid; i < 16777216; i += 524288) {
    float4 x = p[i];
    s += (x.x + x.y) + (x.z + x.w);
    mx = fmaxf(mx, fmaxf(fmaxf(x.x, x.y), fmaxf(x.z, x.w)));
  }
#pragma unroll
  for (int m = 1; m < 64; m <<= 1) {
    s += __shfl_xor(s, m, 64);
    mx = fmaxf(mx, __shfl_xor(mx, m, 64));
  }
  __shared__ float ss[4], sm[4];
  if ((tid & 63) == 0) { ss[tid >> 6] = s; sm[tid >> 6] = mx; }
  __syncthreads();
  if (tid == 0) {
    ws[blockIdx.x]        = (ss[0] + ss[1]) + (ss[2] + ss[3]);
    ws[2048 + blockIdx.x] = fmaxf(fmaxf(sm[0], sm[1]), fmaxf(sm[2], sm[3]));
  }
}

// final reduce + scalar prep + mask-layout detection (byte vs int32 bool)
__global__ __launch_bounds__(256) void red2_kernel(const float* __restrict__ tpw,
                                                   const unsigned* __restrict__ mku,
                                                   float* __restrict__ ws) {
  const int tid = threadIdx.x;
  double s = 0.0; float mx = -1e30f;
  for (int i = tid; i < 2048; i += 256) { s += (double)ws[i]; mx = fmaxf(mx, ws[2048 + i]); }
#pragma unroll
  for (int m = 1; m < 64; m <<= 1) {
    s += __shfl_xor(s, m, 64);
    mx = fmaxf(mx, __shfl_xor(mx, m, 64));
  }
  unsigned big = 0;
  for (int i = tid; i < 1024; i += 256) big |= (mku[i] > 1u) ? 1u : 0u;
  const int anyw = __any(big != 0);
  __shared__ double sd[4]; __shared__ float sm[4]; __shared__ int sa[4];
  if ((tid & 63) == 0) { sd[tid >> 6] = s; sm[tid >> 6] = mx; sa[tid >> 6] = anyw; }
  __syncthreads();
  if (tid == 0) {
    double tot = (sd[0] + sd[1]) + (sd[2] + sd[3]);
    float m4 = fmaxf(fmaxf(sm[0], sm[1]), fmaxf(sm[2], sm[3]));
    double mean = tot / 67108864.0;
    float inv_mean = (float)(1.0 / mean);
    float sp = log1pf(__expf(tpw[0]));
    ws[4096] = inv_mean;
    ws[4098] = (sa[0] | sa[1] | sa[2] | sa[3]) ? 1.f : 0.f;  // 1 = byte mask, 0 = int32
    ws[4099] = 2.718281828459045f + sp * m4 * inv_mean;      // ec = e + bias_c
  }
}

// ---------- fused attn (r8 structure, chunk doubled: 32 j/wave/chunk, 8 chunks) ----------
// 512 thr (8 waves), 16 q-rows/block. Chunk = 256 j; wave w owns j in
// [c*256 + w*32, +32) as TWO 16-j subtiles. Swapped QK^T (mfma(K,Q) -> D[j][q]);
// wave-private K/V via global_load_lds, double-buffered depth-2; td/mask reg prefetch;
// exp2-domain softmax; exact counted vmcnt (in-order-retirement derivation per wait).
// Phase-2 PV MFMAs fully packed (k=0..31 all real). E[8][2] packed bf16 (32 VGPR) —
// fine at the 2-wave tier's 256-reg budget; LDS 138.8 KB -> 1 block/CU (as r8).
__global__ __launch_bounds__(512)
void attn_kernel(
    const float* __restrict__ q, const float* __restrict__ kp, const float* __restrict__ vp,
    const float* __restrict__ td, const unsigned char* __restrict__ maskb,
    const float* __restrict__ tmwp, const float* __restrict__ ws,
    float* __restrict__ out, float* __restrict__ attn) {

  __shared__ float regA[8][2][2048];         // 128 KB: per-wave dbuf K/V chunk (32 rows)
  __shared__ unsigned short Ps[8][16 * 40];  // 10 KB: P bridge, 32 j + pad (80B rows)
  __shared__ float rsum[8][16];

  const int tid  = threadIdx.x;
  const int w    = tid >> 6;
  const int lane = tid & 63;
  const int lrow = lane & 15;
  const int lgrp = lane >> 4;

  const int b     = blockIdx.x >> 7;
  const int qbase = (blockIdx.x & 127) << 4;

  const float inv_mean = ws[4096];
  const float ec       = ws[4099];
  const float tmw      = tmwp[0];
  const float sc       = tmw * 2.0813689810056077f;      // tmw * log2e / ln2
  const int   msh      = (ws[4098] != 0.f) ? 0 : 2;

  const unsigned qrow = (unsigned)(b * LQ_N + qbase + lrow);
  const unsigned tdo0 = (qrow << 11) + (unsigned)(w * 32 + lgrp * 4);
  const unsigned kvo0 = ((unsigned)b << 17) + ((unsigned)w << 11);
  const unsigned pA = (lgrp << 6) + ((lrow ^ lgrp)       << 2);
  const unsigned pB = (lgrp << 6) + ((lrow ^ (lgrp + 4)) << 2);

  // ---- Q fragments: direct load + cvt (r11-proven path) ----
  const float qscale = 0.18033688011112042f;             // 0.125 * log2e
  bf16x8 qa[2];
  {
    const float* qb = q + ((size_t)qrow << 6) + lgrp * 8;
    f32x4 a0 = *reinterpret_cast<const f32x4*>(qb);
    f32x4 a1 = *reinterpret_cast<const f32x4*>(qb + 4);
    f32x4 a2 = *reinterpret_cast<const f32x4*>(qb + 32);
    f32x4 a3 = *reinterpret_cast<const f32x4*>(qb + 36);
    u32x4 k0 = { cvt_pk_bf16(a0[0]*qscale, a0[1]*qscale), cvt_pk_bf16(a0[2]*qscale, a0[3]*qscale),
                 cvt_pk_bf16(a1[0]*qscale, a1[1]*qscale), cvt_pk_bf16(a1[2]*qscale, a1[3]*qscale) };
    u32x4 k1 = { cvt_pk_bf16(a2[0]*qscale, a2[1]*qscale), cvt_pk_bf16(a2[2]*qscale, a2[3]*qscale),
                 cvt_pk_bf16(a3[0]*qscale, a3[1]*qscale), cvt_pk_bf16(a3[2]*qscale, a3[3]*qscale) };
    qa[0] = __builtin_bit_cast(bf16x8, k0);
    qa[1] = __builtin_bit_cast(bf16x8, k1);
  }

  // wave-private DMA: 32 rows x 64 f32 (8 KB) = 8 gl_lds; LDS linear, source permuted
  auto dma = [&](const float* src_base, int c, int pb) {
    const unsigned base = kvo0 + (unsigned)c * 16384u;   // chunk stride = 256 rows
#pragma unroll
    for (int t = 0; t < 8; ++t) {
      const unsigned perm = (t & 1) ? pB : pA;
      gl_lds16(src_base + (base + (unsigned)t * 256u + perm), &regA[w][pb][t * 256]);
    }
  };

  // td 2x float4 (NT) + mask 2x 4-wide = 4 VMEM ops (both layouts)
  auto ldtd = [&](int c, f32x4* tdv, unsigned* mk4) {
    const unsigned to = tdo0 + (unsigned)c * 256u;
    tdv[0] = __builtin_nontemporal_load(reinterpret_cast<const f32x4*>(td + to));
    tdv[1] = __builtin_nontemporal_load(reinterpret_cast<const f32x4*>(td + to + 16));
    if (msh == 0) {
      mk4[0] = *reinterpret_cast<const unsigned*>(maskb + to);
      mk4[1] = *reinterpret_cast<const unsigned*>(maskb + to + 16);
    } else {
      u32x4 m0 = *reinterpret_cast<const u32x4*>(maskb + ((size_t)to << 2));
      u32x4 m1 = *reinterpret_cast<const u32x4*>(maskb + ((size_t)(to + 16u) << 2));
      mk4[0] = (m0[0] & 1u) | ((m0[1] & 1u) << 8) | ((m0[2] & 1u) << 16) | ((m0[3] & 1u) << 24);
      mk4[1] = (m1[0] & 1u) | ((m1[1] & 1u) << 8) | ((m1[2] & 1u) << 16) | ((m1[3] & 1u) << 24);
    }
  };

  // ---- phase 1: QK^T(swapped) + bias + mask + exp2 ----
  // program order: Kd0[8] Kd1[8] L0[4] | iter c: Kd(c+2)[8] (c<6), L(c+1)[4] (c<7)
  dma(kp, 0, 0); SBAR();
  dma(kp, 1, 1); SBAR();
  f32x4    tdb[2][2];
  unsigned mkb[2][2];
  ldtd(0, tdb[0], mkb[0]); SBAR();

  float rs = 0.f;
  u32x2 E[8][2];

#pragma unroll
  for (int c = 0; c < 8; ++c) {
    // TOP: Kd(c) retired. newer(Kd0)={Kd1,L0}=12; steady outstanding={Kd(c+1),L(c)}=12
    // (exact: if Kd(c) outstanding, count>12); c=7: outstanding={L7}=4
    if (c == 7) { WAIT_VMC(4); } else { WAIT_VMC(12); }

    const int x7 = lrow & 7;
    f32x4 acc0 = {0.f, 0.f, 0.f, 0.f};
    f32x4 acc1 = {0.f, 0.f, 0.f, 0.f};
#pragma unroll
    for (int T = 0; T < 2; ++T) {
      const int rr = T * 16 + lrow;            // (rr & 7) == (lrow & 7)
      f32x4 ka0 = *(const f32x4*)&regA[w][c & 1][rr * 64 + ((lgrp * 2    ) ^ x7) * 4];
      f32x4 ka1 = *(const f32x4*)&regA[w][c & 1][rr * 64 + ((lgrp * 2 + 1) ^ x7) * 4];
      f32x4 kb0 = *(const f32x4*)&regA[w][c & 1][rr * 64 + ((8 + lgrp * 2) ^ x7) * 4];
      f32x4 kb1 = *(const f32x4*)&regA[w][c & 1][rr * 64 + ((9 + lgrp * 2) ^ x7) * 4];
      u32x4 kd0 = { cvt_pk_bf16(ka0[0], ka0[1]), cvt_pk_bf16(ka0[2], ka0[3]),
                    cvt_pk_bf16(ka1[0], ka1[1]), cvt_pk_bf16(ka1[2], ka1[3]) };
      u32x4 kd1 = { cvt_pk_bf16(kb0[0], kb0[1]), cvt_pk_bf16(kb0[2], kb0[3]),
                    cvt_pk_bf16(kb1[0], kb1[1]), cvt_pk_bf16(kb1[2], kb1[3]) };
      f32x4& acc = (T == 0) ? acc0 : acc1;
      acc = __builtin_amdgcn_mfma_f32_16x16x32_bf16(__builtin_bit_cast(bf16x8, kd0), qa[0], acc, 0, 0, 0);
      acc = __builtin_amdgcn_mfma_f32_16x16x32_bf16(__builtin_bit_cast(bf16x8, kd1), qa[1], acc, 0, 0, 0);
    }
    WAIT_LGKM0();                              // buffer (c&1) reusable
    if (c < 6) { dma(kp, c + 2, c & 1); SBAR(); }
    if (c < 7) { ldtd(c + 1, tdb[(c + 1) & 1], mkb[(c + 1) & 1]); SBAR(); }

    // MID: L(c) retired. newer(L(c)) = {Kd(c+2)[8], L(c+1)[4]} = 12 (c<=5);
    // c=6: {L7}=4; c=7: 0
    if (c <= 5)      { WAIT_VMC(12); }
    else if (c == 6) { WAIT_VMC(4);  }
    else             { WAIT_VMC(0);  }

#pragma unroll
    for (int T = 0; T < 2; ++T) {
      const f32x4    tv  = tdb[c & 1][T];
      const unsigned mk4 = mkb[c & 1][T];
      float e4[4];
#pragma unroll
      for (int i = 0; i < 4; ++i) {
        const f32x4& acc = (T == 0) ? *(f32x4*)&((T==0)?acc0:acc1) : *(f32x4*)&acc1; // (resolved below)
        (void)acc;
        const float av = (T == 0) ? ((i==0)?acc0[0]:(i==1)?acc0[1]:(i==2)?acc0[2]:acc0[3])
                                  : ((i==0)?acc1[0]:(i==1)?acc1[1]:(i==2)?acc1[2]:acc1[3]);
        const float z  = __builtin_fmaf(tv[i], inv_mean, ec);
        const float l2 = __builtin_amdgcn_logf(z);
        const float r  = __builtin_amdgcn_rcpf(l2);
        const float sv = __builtin_fmaf(sc, r, av);
        const float e  = ((mk4 >> (8 * i)) & 0xffu) ? 0.f : __builtin_amdgcn_exp2f(sv);
        e4[i] = e;
        rs += e;
      }
      E[c][T] = u32x2{ cvt_pk_bf16(e4[0], e4[1]), cvt_pk_bf16(e4[2], e4[3]) };
    }
  }

  // ---- V DMA prologue (drained by the barrier below; harmless) ----
  dma(vp, 0, 0); SBAR();
  dma(vp, 1, 1); SBAR();

  // ---- row sum (q-row = lrow) ----
  rs += __shfl_xor(rs, 16, 64);
  rs += __shfl_xor(rs, 32, 64);
  if (lgrp == 0) rsum[w][lrow] = rs;
  __syncthreads();
  float invl;
  {
    float s = 0.f;
#pragma unroll
    for (int w2 = 0; w2 < 8; ++w2) s += rsum[w2][lrow];
    invl = __fdividef(1.f, s);
  }

  // ---- phase 2: attn write + PV (fully-packed k=32 MFMAs) ----
  f32x4 oacc[4];
#pragma unroll
  for (int n = 0; n < 4; ++n) oacc[n] = {0.f, 0.f, 0.f, 0.f};

#pragma unroll
  for (int c = 0; c < 8; ++c) {
    // TOP: Vd(c) retired. order: Vd0 Vd1 | iter i: Vd(i+2)[8] (i<6), S(i)[2].
    // c=0: newer={Vd1}=8; c=1: newer={Vd2,S0}=10; steady: {S(c-2),Vd(c+1),S(c-1)}=12; c=7: {S5,S6}=4
    if (c == 0)      { WAIT_VMC(8);  }
    else if (c == 1) { WAIT_VMC(10); }
    else if (c == 7) { WAIT_VMC(4);  }
    else             { WAIT_VMC(12); }

    f32x4 pv0, pv1;
    {
      const unsigned e0 = E[c][0][0], e1 = E[c][0][1];
      const unsigned f0 = E[c][1][0], f1 = E[c][1][1];
      pv0[0] = __uint_as_float(e0 << 16)         * invl;
      pv0[1] = __uint_as_float(e0 & 0xffff0000u) * invl;
      pv0[2] = __uint_as_float(e1 << 16)         * invl;
      pv0[3] = __uint_as_float(e1 & 0xffff0000u) * invl;
      pv1[0] = __uint_as_float(f0 << 16)         * invl;
      pv1[1] = __uint_as_float(f0 & 0xffff0000u) * invl;
      pv1[2] = __uint_as_float(f1 << 16)         * invl;
      pv1[3] = __uint_as_float(f1 & 0xffff0000u) * invl;
    }

    // P bridge: row q=lrow, 32 jl slots; tile0 at jl=lgrp*4, tile1 at 16+lgrp*4
    *reinterpret_cast<u32x2*>(&Ps[w][lrow * 40 + lgrp * 4]) =
        u32x2{ cvt_pk_bf16(pv0[0], pv0[1]), cvt_pk_bf16(pv0[2], pv0[3]) };
    *reinterpret_cast<u32x2*>(&Ps[w][lrow * 40 + 16 + lgrp * 4]) =
        u32x2{ cvt_pk_bf16(pv1[0], pv1[1]), cvt_pk_bf16(pv1[2], pv1[3]) };

    // A-fragment: k = lgrp*8+e, all 32 real
    const bf16x8 pa = *(const bf16x8*)&Ps[w][lrow * 40 + lgrp * 8];

#pragma unroll
    for (int n = 0; n < 4; ++n) {
      float vv[8];
#pragma unroll
      for (int e = 0; e < 8; ++e) {
        const int r    = lgrp * 8 + e;          // V local row = k (0..31)
        const int dcol = n * 16 + lrow;
        const int slot = (dcol >> 2) ^ (r & 7);
        vv[e] = regA[w][c & 1][r * 64 + slot * 4 + (dcol & 3)];
      }
      u32x4 vd = { cvt_pk_bf16(vv[0], vv[1]), cvt_pk_bf16(vv[2], vv[3]),
                   cvt_pk_bf16(vv[4], vv[5]), cvt_pk_bf16(vv[6], vv[7]) };
      oacc[n] = __builtin_amdgcn_mfma_f32_16x16x32_bf16(pa, __builtin_bit_cast(bf16x8, vd),
                                                        oacc[n], 0, 0, 0);
    }

    WAIT_LGKM0();                              // regA[c&1] reads done
    if (c < 6) { dma(vp, c + 2, c & 1); SBAR(); }

    const unsigned to = tdo0 + (unsigned)c * 256u;
    __builtin_nontemporal_store(pv0, reinterpret_cast<f32x4*>(attn + to));
    __builtin_nontemporal_store(pv1, reinterpret_cast<f32x4*>(attn + to + 16));
  }

  // ---- cross-wave O reduction (reuse regA[.][0]) ----
  __syncthreads();
#pragma unroll
  for (int n = 0; n < 4; ++n)
#pragma unroll
    for (int i = 0; i < 4; ++i)
      regA[w][0][(lgrp * 4 + i) * 64 + n * 16 + lrow] = oacc[n][i];
  __syncthreads();
  for (int i2 = tid; i2 < 1024; i2 += 512) {
    float s = 0.f;
#pragma unroll
    for (int w2 = 0; w2 < 8; ++w2) s += regA[w2][0][i2];
    out[((size_t)(b * LQ_N + qbase) << 6) + i2] = s;
  }
}

extern "C" void kernel_launch(void* const* d_in, const int* in_sizes, int n_in,
                              void* d_out, int out_size, void* d_ws, size_t ws_size,
                              hipStream_t stream) {
  const float* q   = (const float*)d_in[0];
  const float* k   = (const float*)d_in[1];
  const float* v   = (const float*)d_in[2];
  const float* td  = (const float*)d_in[3];
  const unsigned char* mask = (const unsigned char*)d_in[4];
  const float* tpw = (const float*)d_in[5];
  const float* tmw = (const float*)d_in[6];
  float* out  = (float*)d_out;
  float* attn = out + (size_t)B_N * LQ_N * D_N;
  float* wsf  = (float*)d_ws;

  red1_kernel<<<2048, 256, 0, stream>>>(td, wsf);
  red2_kernel<<<1, 256, 0, stream>>>(tpw, (const unsigned*)mask, wsf);
  attn_kernel<<<2048, 512, 0, stream>>>(q, k, v, td, mask, tmw, wsf, out, attn);
}